// Round 1
// baseline (243.867 us; speedup 1.0000x reference)
//
#include <hip/hip_runtime.h>
#include <hip/hip_bf16.h>

#define TT 2048
#define DDIM 1024
#define NHEAD 16
#define HD 64
#define QBLK 64
#define KBLK 32

typedef float f32x4 __attribute__((ext_vector_type(4)));
typedef short bf16x8 __attribute__((ext_vector_type(8)));

__device__ __forceinline__ ushort f2bf(float f) {
    union { float f; unsigned u; } x; x.f = f;
    unsigned u = x.u;
    return (ushort)((u + 0x7FFFu + ((u >> 16) & 1u)) >> 16);
}

__global__ __launch_bounds__(256, 2)
void alibi_attn_kernel(const float* __restrict__ qg,
                       const float* __restrict__ kg,
                       const float* __restrict__ vg,
                       float* __restrict__ out) {
    // LDS: K tile swizzled row-major [32][64]; V tile transposed [64][56-pad];
    // per-wave P buffers [16][40-pad]
    __shared__ __align__(16) ushort lds_k[KBLK * HD];
    __shared__ __align__(16) ushort lds_vt[HD * 56];
    __shared__ __align__(16) ushort lds_p[4 * 16 * 40];

    const int tid  = threadIdx.x;
    const int wv   = tid >> 6;
    const int lane = tid & 63;
    const int g    = lane >> 4;   // 0..3
    const int r16  = lane & 15;   // 0..15

    // reversed q-tile order: heavy (long-causal) blocks first
    const int qt = (int)gridDim.x - 1 - (int)blockIdx.x;
    const int q0 = qt * QBLK;
    const int bh = blockIdx.y;
    const int b  = bh >> 4;
    const int h  = bh & 15;

    const float LOG2E  = 1.4426950408889634f;
    const float slope2 = exp2f(-0.5f * (float)(h + 1)) * LOG2E; // alibi slope * log2e
    const float sc2    = 0.125f * LOG2E;                        // 1/sqrt(64) * log2e

    // Q A-fragments (rows q0+wv*16+r16, two d-chunks of 32)
    const int t_a = q0 + wv * 16 + r16;
    bf16x8 qf[2];
    {
        const float* gq = qg + ((size_t)(b * TT + t_a)) * DDIM + h * HD + g * 8;
        #pragma unroll
        for (int ch = 0; ch < 2; ++ch) {
            float4 a0 = *(const float4*)(gq + ch * 32);
            float4 a1 = *(const float4*)(gq + ch * 32 + 4);
            bf16x8 w;
            w[0]=f2bf(a0.x); w[1]=f2bf(a0.y); w[2]=f2bf(a0.z); w[3]=f2bf(a0.w);
            w[4]=f2bf(a1.x); w[5]=f2bf(a1.y); w[6]=f2bf(a1.z); w[7]=f2bf(a1.w);
            qf[ch] = w;
        }
    }

    f32x4 oacc[4] = {};           // O accum: 4 dv-tiles x 4 rows
    float mrun[4], lrun[4];
    #pragma unroll
    for (int r = 0; r < 4; ++r) { mrun[r] = -INFINITY; lrun[r] = 0.f; }

    const int n_kv = q0 / KBLK + 2;   // tiles with kv0 <= q0+63
    const int srow = tid >> 3;        // 0..31 staging row
    const int cg   = tid & 7;         // 0..7 col group of 8

    for (int it = 0; it < n_kv; ++it) {
        const int kv0 = it * KBLK;
        __syncthreads();
        // ---- stage K (swizzled) and V (transposed) ----
        {
            const size_t grow = ((size_t)(b * TT + kv0 + srow)) * DDIM + h * HD + cg * 8;
            float4 a0 = *(const float4*)(kg + grow);
            float4 a1 = *(const float4*)(kg + grow + 4);
            bf16x8 w8;
            w8[0]=f2bf(a0.x); w8[1]=f2bf(a0.y); w8[2]=f2bf(a0.z); w8[3]=f2bf(a0.w);
            w8[4]=f2bf(a1.x); w8[5]=f2bf(a1.y); w8[6]=f2bf(a1.z); w8[7]=f2bf(a1.w);
            *(bf16x8*)&lds_k[srow * 64 + (((cg) ^ (srow & 7)) << 3)] = w8;

            float4 b0 = *(const float4*)(vg + grow);
            float4 b1 = *(const float4*)(vg + grow + 4);
            float vals[8] = {b0.x,b0.y,b0.z,b0.w,b1.x,b1.y,b1.z,b1.w};
            #pragma unroll
            for (int i = 0; i < 8; ++i)
                lds_vt[(cg * 8 + i) * 56 + srow] = f2bf(vals[i]);
        }
        __syncthreads();

        // ---- S = Q K^T (two 16x16 col-tiles, two d-chunks each) ----
        f32x4 s_acc[2] = {};
        #pragma unroll
        for (int ct = 0; ct < 2; ++ct) {
            const int krow = ct * 16 + r16;
            #pragma unroll
            for (int ch = 0; ch < 2; ++ch) {
                const int slot = (ch * 4 + g) ^ (krow & 7);
                bf16x8 kf = *(const bf16x8*)&lds_k[krow * 64 + slot * 8];
                s_acc[ct] = __builtin_amdgcn_mfma_f32_16x16x32_bf16(qf[ch], kf, s_acc[ct], 0, 0, 0);
            }
        }

        // ---- online softmax (rows 4g+r, cols r16 / r16+16) ----
        const int wpb = wv * (16 * 40);
        #pragma unroll
        for (int r = 0; r < 4; ++r) {
            const int ti  = q0 + wv * 16 + 4 * g + r;
            const int si0 = kv0 + r16;
            const int si1 = kv0 + 16 + r16;
            float x0 = (si0 <= ti) ? (s_acc[0][r] * sc2 + (float)(si0 - ti) * slope2) : -INFINITY;
            float x1 = (si1 <= ti) ? (s_acc[1][r] * sc2 + (float)(si1 - ti) * slope2) : -INFINITY;
            float tm = fmaxf(x0, x1);
            tm = fmaxf(tm, __shfl_xor(tm, 1));
            tm = fmaxf(tm, __shfl_xor(tm, 2));
            tm = fmaxf(tm, __shfl_xor(tm, 4));
            tm = fmaxf(tm, __shfl_xor(tm, 8));
            const float mnew = fmaxf(mrun[r], tm);
            const float fsc  = exp2f(mrun[r] - mnew);   // first tile: exp2(-inf)=0, safe
            mrun[r] = mnew;
            const float p0 = exp2f(x0 - mnew);
            const float p1 = exp2f(x1 - mnew);
            float ps = p0 + p1;
            ps += __shfl_xor(ps, 1);
            ps += __shfl_xor(ps, 2);
            ps += __shfl_xor(ps, 4);
            ps += __shfl_xor(ps, 8);
            lrun[r] = lrun[r] * fsc + ps;
            #pragma unroll
            for (int dt = 0; dt < 4; ++dt) oacc[dt][r] *= fsc;
            lds_p[wpb + (4 * g + r) * 40 + r16]      = f2bf(p0);
            lds_p[wpb + (4 * g + r) * 40 + 16 + r16] = f2bf(p1);
        }

        // ---- O += P V (K-dim = 32, one MFMA per dv-tile) ----
        bf16x8 pa = *(const bf16x8*)&lds_p[wpb + r16 * 40 + g * 8];
        #pragma unroll
        for (int dt = 0; dt < 4; ++dt) {
            bf16x8 vb = *(const bf16x8*)&lds_vt[(dt * 16 + r16) * 56 + g * 8];
            oacc[dt] = __builtin_amdgcn_mfma_f32_16x16x32_bf16(pa, vb, oacc[dt], 0, 0, 0);
        }
    }

    // ---- epilogue: normalize and store ----
    #pragma unroll
    for (int r = 0; r < 4; ++r) {
        const int ti  = q0 + wv * 16 + 4 * g + r;
        const float inv = 1.0f / lrun[r];
        float* go = out + ((size_t)(b * TT + ti)) * DDIM + h * HD;
        #pragma unroll
        for (int dt = 0; dt < 4; ++dt)
            go[dt * 16 + r16] = oacc[dt][r] * inv;
    }
}

extern "C" void kernel_launch(void* const* d_in, const int* in_sizes, int n_in,
                              void* d_out, int out_size, void* d_ws, size_t ws_size,
                              hipStream_t stream) {
    (void)in_sizes; (void)n_in; (void)d_ws; (void)ws_size; (void)out_size;
    const float* q = (const float*)d_in[0];
    const float* k = (const float*)d_in[1];
    const float* v = (const float*)d_in[2];
    float* o = (float*)d_out;
    dim3 grid(TT / QBLK, 2 * NHEAD);
    alibi_attn_kernel<<<grid, 256, 0, stream>>>(q, k, v, o);
}

// Round 2
// 125.546 us; speedup vs baseline: 1.9425x; 1.9425x over previous
//
#include <hip/hip_runtime.h>
#include <hip/hip_bf16.h>

#define TT 2048
#define DDIM 1024
#define NHEAD 16
#define HD 64
#define QBLK 128
#define KVBLK 64
#define NWAVE 8
#define VST 72   // u16 stride for V^T rows and P rows (144B, 16B-aligned, bank-spreading)

typedef float f32x4 __attribute__((ext_vector_type(4)));
typedef short bf16x8 __attribute__((ext_vector_type(8)));

__device__ __forceinline__ ushort f2bf(float f) {
    __hip_bfloat16 h = __float2bfloat16(f);
    return *reinterpret_cast<ushort*>(&h);
}

__global__ __launch_bounds__(512, 2)
void alibi_attn_kernel(const float* __restrict__ qg,
                       const float* __restrict__ kg,
                       const float* __restrict__ vg,
                       float* __restrict__ out) {
    // double-buffered K (row-major, XOR-swizzled) and V^T (transposed, XOR-swizzled);
    // per-wave P buffers
    __shared__ __align__(16) ushort lds_k[2][KVBLK * HD];
    __shared__ __align__(16) ushort lds_vt[2][HD * VST];
    __shared__ __align__(16) ushort lds_p[NWAVE][16 * VST];

    const int tid  = threadIdx.x;
    const int wv   = tid >> 6;
    const int lane = tid & 63;
    const int g    = lane >> 4;   // 0..3
    const int r16  = lane & 15;   // 0..15

    const int qt = (int)gridDim.x - 1 - (int)blockIdx.x;   // heavy q-tiles first
    const int q0 = qt * QBLK;
    const int bh = blockIdx.y;
    const int b  = bh >> 4;
    const int h  = bh & 15;

    const float LOG2E  = 1.4426950408889634f;
    const float slope2 = exp2f(-0.5f * (float)(h + 1)) * LOG2E; // alibi slope * log2e
    const float sc2    = 0.125f * LOG2E;                        // 1/sqrt(64) * log2e

    // ---- Q fragments: wave rows q0 + wv*16 + r16, two d-chunks of 32 ----
    bf16x8 qf[2];
    {
        const float* gq = qg + ((size_t)(b * TT + q0 + wv * 16 + r16)) * DDIM + h * HD + g * 8;
        #pragma unroll
        for (int ch = 0; ch < 2; ++ch) {
            float4 a0 = *(const float4*)(gq + ch * 32);
            float4 a1 = *(const float4*)(gq + ch * 32 + 4);
            bf16x8 w;
            w[0]=f2bf(a0.x); w[1]=f2bf(a0.y); w[2]=f2bf(a0.z); w[3]=f2bf(a0.w);
            w[4]=f2bf(a1.x); w[5]=f2bf(a1.y); w[6]=f2bf(a1.z); w[7]=f2bf(a1.w);
            qf[ch] = w;
        }
    }

    // ---- staging geometry: 512 threads cover 64 rows x 8 col-groups ----
    const int srow = tid >> 3;   // 0..63
    const int cg   = tid & 7;    // 0..7
    const size_t gbase = (size_t)(b * TT) * DDIM + h * HD + cg * 8;

    f32x4 oacc[4] = {};
    float mrun[4], lrun[4];
    #pragma unroll
    for (int r = 0; r < 4; ++r) { mrun[r] = -INFINITY; lrun[r] = 0.f; }

    const int n_kv  = q0 / KVBLK + 2;
    const int qlast = q0 + wv * 16 + 15;   // last q-row this wave owns

    float4 kr0, kr1, vr0, vr1;   // staging registers (next tile)
    // prologue: stage tile 0
    {
        const float* kp = kg + gbase + (size_t)srow * DDIM;
        const float* vp = vg + gbase + (size_t)srow * DDIM;
        kr0 = *(const float4*)kp; kr1 = *(const float4*)(kp + 4);
        vr0 = *(const float4*)vp; vr1 = *(const float4*)(vp + 4);
    }
    {
        bf16x8 w;
        w[0]=f2bf(kr0.x); w[1]=f2bf(kr0.y); w[2]=f2bf(kr0.z); w[3]=f2bf(kr0.w);
        w[4]=f2bf(kr1.x); w[5]=f2bf(kr1.y); w[6]=f2bf(kr1.z); w[7]=f2bf(kr1.w);
        *(bf16x8*)&lds_k[0][srow * 64 + ((cg ^ (srow & 7)) << 3)] = w;
        float va[8] = {vr0.x,vr0.y,vr0.z,vr0.w,vr1.x,vr1.y,vr1.z,vr1.w};
        const int colw = srow ^ (cg << 3);
        #pragma unroll
        for (int i = 0; i < 8; ++i)
            lds_vt[0][(cg * 8 + i) * VST + colw] = f2bf(va[i]);
    }
    int cur = 0;

    for (int it = 0; it < n_kv; ++it) {
        const int kv0 = it * KVBLK;
        const bool pre = (it + 1 < n_kv);
        if (pre) {  // issue next-tile loads BEFORE the barrier; consume after compute
            const float* kp = kg + gbase + (size_t)(kv0 + KVBLK + srow) * DDIM;
            const float* vp = vg + gbase + (size_t)(kv0 + KVBLK + srow) * DDIM;
            kr0 = *(const float4*)kp; kr1 = *(const float4*)(kp + 4);
            vr0 = *(const float4*)vp; vr1 = *(const float4*)(vp + 4);
        }
        __syncthreads();   // buf[cur] writes visible; everyone done reading buf[cur^1]

        if (kv0 <= qlast) {   // wave-uniform causal skip
            // ---- S = Q K^T : 4 col-tiles x 2 d-chunks ----
            f32x4 s_acc[4] = {};
            #pragma unroll
            for (int ct = 0; ct < 4; ++ct) {
                if (kv0 + ct * 16 <= qlast) {
                    const int krow = ct * 16 + r16;
                    #pragma unroll
                    for (int ch = 0; ch < 2; ++ch) {
                        bf16x8 kf = *(const bf16x8*)&lds_k[cur][krow * 64 + ((((ch << 2) + g) ^ (krow & 7)) << 3)];
                        s_acc[ct] = __builtin_amdgcn_mfma_f32_16x16x32_bf16(qf[ch], kf, s_acc[ct], 0, 0, 0);
                    }
                }
            }
            // ---- online softmax: rows 4g+r, cols ct*16 + r16 ----
            #pragma unroll
            for (int r = 0; r < 4; ++r) {
                const int ti = q0 + wv * 16 + 4 * g + r;
                const float base = (float)(kv0 + r16 - ti);
                float x[4];
                #pragma unroll
                for (int ct = 0; ct < 4; ++ct) {
                    const bool valid = (kv0 + ct * 16 + r16 <= ti);
                    x[ct] = valid ? s_acc[ct][r] * sc2 + (base + 16.f * ct) * slope2 : -INFINITY;
                }
                float tm = fmaxf(fmaxf(x[0], x[1]), fmaxf(x[2], x[3]));
                tm = fmaxf(tm, __shfl_xor(tm, 1));
                tm = fmaxf(tm, __shfl_xor(tm, 2));
                tm = fmaxf(tm, __shfl_xor(tm, 4));
                tm = fmaxf(tm, __shfl_xor(tm, 8));
                const float mnew = fmaxf(mrun[r], tm);
                const float fsc  = exp2f(mrun[r] - mnew);
                mrun[r] = mnew;
                float p0 = exp2f(x[0] - mnew), p1 = exp2f(x[1] - mnew);
                float p2 = exp2f(x[2] - mnew), p3 = exp2f(x[3] - mnew);
                float ps = (p0 + p1) + (p2 + p3);
                ps += __shfl_xor(ps, 1);
                ps += __shfl_xor(ps, 2);
                ps += __shfl_xor(ps, 4);
                ps += __shfl_xor(ps, 8);
                lrun[r] = lrun[r] * fsc + ps;
                #pragma unroll
                for (int dt = 0; dt < 4; ++dt) oacc[dt][r] *= fsc;
                ushort* pp = &lds_p[wv][(4 * g + r) * VST + r16];
                pp[0]  = f2bf(p0); pp[16] = f2bf(p1);
                pp[32] = f2bf(p2); pp[48] = f2bf(p3);
            }
            // ---- O += P V : 2 kv-halves x 4 dv-tiles ----
            #pragma unroll
            for (int ks = 0; ks < 2; ++ks) {
                if (kv0 + ks * 32 <= qlast) {
                    bf16x8 pa = *(const bf16x8*)&lds_p[wv][r16 * VST + ks * 32 + g * 8];
                    #pragma unroll
                    for (int dt = 0; dt < 4; ++dt) {
                        const int dv = dt * 16 + r16;
                        bf16x8 vb = *(const bf16x8*)&lds_vt[cur][dv * VST + ((((ks << 2) + g) ^ ((dv >> 3) & 7)) << 3)];
                        oacc[dt] = __builtin_amdgcn_mfma_f32_16x16x32_bf16(pa, vb, oacc[dt], 0, 0, 0);
                    }
                }
            }
        }

        if (pre) {  // write staged tile into the other buffer (no race: nobody reads it)
            bf16x8 w;
            w[0]=f2bf(kr0.x); w[1]=f2bf(kr0.y); w[2]=f2bf(kr0.z); w[3]=f2bf(kr0.w);
            w[4]=f2bf(kr1.x); w[5]=f2bf(kr1.y); w[6]=f2bf(kr1.z); w[7]=f2bf(kr1.w);
            *(bf16x8*)&lds_k[cur ^ 1][srow * 64 + ((cg ^ (srow & 7)) << 3)] = w;
            float va[8] = {vr0.x,vr0.y,vr0.z,vr0.w,vr1.x,vr1.y,vr1.z,vr1.w};
            const int colw = srow ^ (cg << 3);
            #pragma unroll
            for (int i = 0; i < 8; ++i)
                lds_vt[cur ^ 1][(cg * 8 + i) * VST + colw] = f2bf(va[i]);
        }
        cur ^= 1;
    }

    // ---- epilogue: normalize and store ----
    #pragma unroll
    for (int r = 0; r < 4; ++r) {
        const int ti = q0 + wv * 16 + 4 * g + r;
        const float inv = 1.0f / lrun[r];
        float* go = out + ((size_t)(b * TT + ti)) * DDIM + h * HD;
        #pragma unroll
        for (int dt = 0; dt < 4; ++dt)
            go[dt * 16 + r16] = oacc[dt][r] * inv;
    }
}

extern "C" void kernel_launch(void* const* d_in, const int* in_sizes, int n_in,
                              void* d_out, int out_size, void* d_ws, size_t ws_size,
                              hipStream_t stream) {
    (void)in_sizes; (void)n_in; (void)d_ws; (void)ws_size; (void)out_size;
    const float* q = (const float*)d_in[0];
    const float* k = (const float*)d_in[1];
    const float* v = (const float*)d_in[2];
    float* o = (float*)d_out;
    dim3 grid(TT / QBLK, 2 * NHEAD);
    alibi_attn_kernel<<<grid, 512, 0, stream>>>(q, k, v, o);
}

// Round 3
// 86.523 us; speedup vs baseline: 2.8185x; 1.4510x over previous
//
#include <hip/hip_runtime.h>
#include <hip/hip_bf16.h>

#define TT 2048
#define DDIM 1024
#define NHEAD 16
#define HD 64
#define QBLK 64
#define KVBLK 64
#define NWAVE 4
#define VST 72
#define NQT (TT / QBLK)

typedef float f32x4 __attribute__((ext_vector_type(4)));
typedef short bf16x8 __attribute__((ext_vector_type(8)));

__device__ __forceinline__ ushort f2bf(float f) {
    __hip_bfloat16 h = __float2bfloat16(f);
    return *reinterpret_cast<ushort*>(&h);
}

__global__ __launch_bounds__(256, 2)
void alibi_attn_kernel(const float* __restrict__ qg,
                       const float* __restrict__ kg,
                       const float* __restrict__ vg,
                       float* __restrict__ out) {
    // K: row-major [64][64] XOR-swizzled; V^T: [64 dv][VST] XOR-swizzled; P per wave
    __shared__ __align__(16) ushort lds_k[2][KVBLK * HD];
    __shared__ __align__(16) ushort lds_vt[2][HD * VST];
    __shared__ __align__(16) ushort lds_p[NWAVE][16 * VST];

    const int tid  = threadIdx.x;
    const int wv   = tid >> 6;
    const int lane = tid & 63;
    const int hi   = lane >> 4;   // 0..3
    const int qr   = lane & 15;   // 0..15

    // pair (x, 31-x): uniform 33 kv-iterations per block
    const int qtA  = blockIdx.x;
    const int qtB  = NQT - 1 - qtA;
    const int nA   = qtA + 1;
    const int ntot = nA + qtB + 1;   // 33

    const int bh = blockIdx.y;
    const int b  = bh >> 4;
    const int h  = bh & 15;

    const float LOG2E  = 1.4426950408889634f;
    const float slope2 = exp2f(-0.5f * (float)(h + 1)) * LOG2E;
    const float sc2    = 0.125f * LOG2E;

    const size_t bhbase = (size_t)(b * TT) * DDIM + (size_t)(h * HD);

    // staging decomposition (2 slots/thread):
    // K: slot = tid, tid+256 -> row = slot>>3 (0..63), cg = slot&7
    const int krow = tid >> 3;
    const int kcg  = tid & 7;
    // V: slot = tid, tid+256 -> dv = slot&63, kc = slot>>6 (0..7); per-wave coalesced rows
    const int vdv  = tid & 63;
    const int vkc  = tid >> 6;   // 0..3 ; second slot +4

    float ka[2][8], va[2][8];

    auto issue_loads = [&](int kv0) {
        const float* kp0 = kg + bhbase + (size_t)(kv0 + krow) * DDIM + kcg * 8;
        const float* kp1 = kp0 + (size_t)32 * DDIM;
        *(float4*)&ka[0][0] = *(const float4*)kp0; *(float4*)&ka[0][4] = *(const float4*)(kp0 + 4);
        *(float4*)&ka[1][0] = *(const float4*)kp1; *(float4*)&ka[1][4] = *(const float4*)(kp1 + 4);
        const float* vp0 = vg + bhbase + (size_t)(kv0 + vkc * 8) * DDIM + vdv;
        const float* vp1 = vp0 + (size_t)32 * DDIM;
        #pragma unroll
        for (int jj = 0; jj < 8; ++jj) {
            va[0][jj] = vp0[(size_t)jj * DDIM];
            va[1][jj] = vp1[(size_t)jj * DDIM];
        }
    };
    auto write_stage = [&](int nb) {
        #pragma unroll
        for (int s = 0; s < 2; ++s) {
            bf16x8 w;
            #pragma unroll
            for (int e = 0; e < 8; ++e) w[e] = f2bf(ka[s][e]);
            const int row = krow + s * 32;
            *(bf16x8*)&lds_k[nb][row * 64 + ((kcg ^ (row & 7)) << 3)] = w;
            bf16x8 u;
            #pragma unroll
            for (int e = 0; e < 8; ++e) u[e] = f2bf(va[s][e]);
            const int kc = vkc + s * 4;
            const int c  = kc ^ ((vdv >> 3) & 7);
            *(bf16x8*)&lds_vt[nb][vdv * VST + c * 8] = u;
        }
    };

    issue_loads(qtA * KVBLK);
    write_stage(0);
    int cur = 0;

    bf16x8 qf[2];
    f32x4 oacc[4];
    float mrun = -INFINITY, lrun = 0.f;
    int q0 = 0;

    for (int j = 0; j < ntot; ++j) {
        const bool pstart = (j == 0) || (j == nA);
        const bool pend   = (j == nA - 1) || (j == ntot - 1);
        const int  qt     = (j < nA) ? qtA : qtB;
        const int  it     = (j < nA) ? (qtA - j) : (qtB - (j - nA));   // descending kv
        const int  kv0    = it * KVBLK;

        if (j + 1 < ntot) {   // prefetch next tile into regs (hides HBM under compute)
            const int itn = (j + 1 < nA) ? (qtA - j - 1) : (qtB - (j + 1 - nA));
            issue_loads(itn * KVBLK);
        }

        if (pstart) {   // new q-tile: load Q frags, reset state
            q0 = qt * QBLK;
            const float* gq = qg + bhbase + (size_t)(q0 + wv * 16 + qr) * DDIM + hi * 8;
            #pragma unroll
            for (int ch = 0; ch < 2; ++ch) {
                float4 a0 = *(const float4*)(gq + ch * 32);
                float4 a1 = *(const float4*)(gq + ch * 32 + 4);
                bf16x8 w;
                w[0]=f2bf(a0.x); w[1]=f2bf(a0.y); w[2]=f2bf(a0.z); w[3]=f2bf(a0.w);
                w[4]=f2bf(a1.x); w[5]=f2bf(a1.y); w[6]=f2bf(a1.z); w[7]=f2bf(a1.w);
                qf[ch] = w;
            }
            #pragma unroll
            for (int dt = 0; dt < 4; ++dt) oacc[dt] = (f32x4){0.f, 0.f, 0.f, 0.f};
            mrun = -INFINITY; lrun = 0.f;
        }

        __syncthreads();

        const bool diag = (kv0 == q0);   // first (descending) iter of each pass

        // ---- S^T = K Q^T (swapped operands): col = q = qr, row = kv = hi*4+reg ----
        f32x4 s_acc[4] = {};
        __builtin_amdgcn_s_setprio(1);
        #pragma unroll
        for (int st = 0; st < 4; ++st) {
            if (!diag || st <= wv) {
                const int kvrow = st * 16 + qr;
                #pragma unroll
                for (int ch = 0; ch < 2; ++ch) {
                    bf16x8 kf = *(const bf16x8*)&lds_k[cur][kvrow * 64 + ((((ch << 2) + hi) ^ (kvrow & 7)) << 3)];
                    s_acc[st] = __builtin_amdgcn_mfma_f32_16x16x32_bf16(kf, qf[ch], s_acc[st], 0, 0, 0);
                }
            }
        }
        __builtin_amdgcn_s_setprio(0);

        // ---- in-register online softmax (lane owns q-row qr, 16 kv values) ----
        const int ti = q0 + wv * 16 + qr;
        float xv[16];
        float tm = -INFINITY;
        {
            const float relb = (float)(kv0 - ti);
            #pragma unroll
            for (int st = 0; st < 4; ++st)
                #pragma unroll
                for (int r = 0; r < 4; ++r) {
                    const float rel = relb + (float)(st * 16 + hi * 4 + r);
                    float v = s_acc[st][r] * sc2 + rel * slope2;
                    if (diag) v = (rel <= 0.f) ? v : -INFINITY;
                    xv[st * 4 + r] = v;
                    tm = fmaxf(tm, v);
                }
        }
        tm = fmaxf(tm, __shfl_xor(tm, 16));
        tm = fmaxf(tm, __shfl_xor(tm, 32));
        if (!__all(tm <= mrun + 8.f)) {   // defer-max: rare with descending kv
            const float mnew = fmaxf(mrun, tm);
            const float fsc  = exp2f(mrun - mnew);
            mrun = mnew;
            lrun *= fsc;
            float fo[4];
            #pragma unroll
            for (int r = 0; r < 4; ++r) fo[r] = __shfl(fsc, hi * 4 + r);
            #pragma unroll
            for (int dt = 0; dt < 4; ++dt)
                #pragma unroll
                for (int r = 0; r < 4; ++r) oacc[dt][r] *= fo[r];
        }
        float psum = 0.f;
        #pragma unroll
        for (int i = 0; i < 16; ++i) { xv[i] = exp2f(xv[i] - mrun); psum += xv[i]; }
        lrun += psum;

        // ---- P^T -> P in LDS (4x ds_write_b64, consecutive kv packed) ----
        #pragma unroll
        for (int st = 0; st < 4; ++st) {
            ushort4 w;
            w.x = f2bf(xv[st * 4 + 0]); w.y = f2bf(xv[st * 4 + 1]);
            w.z = f2bf(xv[st * 4 + 2]); w.w = f2bf(xv[st * 4 + 3]);
            *(ushort4*)&lds_p[wv][qr * VST + st * 16 + hi * 4] = w;
        }

        // ---- O += P V ----
        __builtin_amdgcn_s_setprio(1);
        #pragma unroll
        for (int ks = 0; ks < 2; ++ks) {
            if (!diag || wv >= 2 || ks == 0) {
                bf16x8 pa = *(const bf16x8*)&lds_p[wv][qr * VST + ks * 32 + hi * 8];
                #pragma unroll
                for (int dt = 0; dt < 4; ++dt) {
                    const int dv = dt * 16 + qr;
                    bf16x8 vb = *(const bf16x8*)&lds_vt[cur][dv * VST + ((((ks << 2) + hi) ^ ((dv >> 3) & 7)) << 3)];
                    oacc[dt] = __builtin_amdgcn_mfma_f32_16x16x32_bf16(pa, vb, oacc[dt], 0, 0, 0);
                }
            }
        }
        __builtin_amdgcn_s_setprio(0);

        if (pend) {   // epilogue for this q-tile
            float lr = lrun;
            lr += __shfl_xor(lr, 16);
            lr += __shfl_xor(lr, 32);
            const float linv = 1.0f / lr;
            #pragma unroll
            for (int r = 0; r < 4; ++r) {
                const float inv = __shfl(linv, hi * 4 + r);
                float* go = out + bhbase + (size_t)(q0 + wv * 16 + hi * 4 + r) * DDIM;
                #pragma unroll
                for (int dt = 0; dt < 4; ++dt)
                    go[dt * 16 + qr] = oacc[dt][r] * inv;
            }
        }

        if (j + 1 < ntot) write_stage(cur ^ 1);
        cur ^= 1;
    }
}

extern "C" void kernel_launch(void* const* d_in, const int* in_sizes, int n_in,
                              void* d_out, int out_size, void* d_ws, size_t ws_size,
                              hipStream_t stream) {
    (void)in_sizes; (void)n_in; (void)d_ws; (void)ws_size; (void)out_size;
    const float* q = (const float*)d_in[0];
    const float* k = (const float*)d_in[1];
    const float* v = (const float*)d_in[2];
    float* o = (float*)d_out;
    dim3 grid(NQT / 2, 2 * NHEAD);
    alibi_attn_kernel<<<grid, 256, 0, stream>>>(q, k, v, o);
}